// Round 4
// baseline (72.750 us; speedup 1.0000x reference)
//
#include <hip/hip_runtime.h>
#include <hip/hip_bf16.h>

// Sliding-window causal attention, B=4, S=4096, d=64, window [i-256, i].
// Round 4: whole 320-key window prestaged to LDS once -> compute phase has
// ZERO barriers. Q fragments loaded global->reg directly (stripe-private).
// 512-thread blocks (8 waves = 4 q-stripes x 2 key-groups), key-split with
// end merge. DPP softmax reductions.
// MFMA layouts (HW-verified): A[m=lane&15][k=quad*8+j]; C/D col=lane&15,
// row=quad*4+reg.

#define LOG2E 1.4426950408889634f

typedef __attribute__((ext_vector_type(8))) short  frag;    // 8 bf16
typedef __attribute__((ext_vector_type(4))) float  f32x4;   // C/D

static __device__ inline short f2bf(float x) {
    __hip_bfloat16 h = __float2bfloat16(x);   // RTNE
    return __builtin_bit_cast(short, h);
}

static __device__ inline frag cvt8(float4 a, float4 b, float sc) {
    frag f;
    f[0] = f2bf(a.x * sc); f[1] = f2bf(a.y * sc);
    f[2] = f2bf(a.z * sc); f[3] = f2bf(a.w * sc);
    f[4] = f2bf(b.x * sc); f[5] = f2bf(b.y * sc);
    f[6] = f2bf(b.z * sc); f[7] = f2bf(b.w * sc);
    return f;
}

// DPP 16-lane reductions (xor1, xor2, half-mirror, mirror)
#define DPPF(x, ctrl) __builtin_bit_cast(float, \
    __builtin_amdgcn_mov_dpp(__builtin_bit_cast(int, (x)), (ctrl), 0xF, 0xF, true))

static __device__ inline float red16_max(float x) {
    x = fmaxf(x, DPPF(x, 0xB1));
    x = fmaxf(x, DPPF(x, 0x4E));
    x = fmaxf(x, DPPF(x, 0x141));
    x = fmaxf(x, DPPF(x, 0x140));
    return x;
}
static __device__ inline float red16_sum(float x) {
    x += DPPF(x, 0xB1);
    x += DPPF(x, 0x4E);
    x += DPPF(x, 0x141);
    x += DPPF(x, 0x140);
    return x;
}

#define KSTR 72    // K row stride (bf16): 144 B, 16B-aligned rows
#define VSTR 328   // Vt row stride (bf16): 656 B, 16B-aligned rows
#define PSTR 40    // P row stride (bf16): 80 B
#define OSTR 65    // merge buffer row stride (fp32)

__global__ __launch_bounds__(512, 2) void swa_mfma3(const float* __restrict__ qkv,
                                                    float* __restrict__ out)
{
    __shared__ short Ks[320 * KSTR];      // 45 KB: rows 64c + key
    __shared__ short Vt[64 * VSTR];       // 41 KB: Vt[dim][64c + key]
    __shared__ short Pw[8][16 * PSTR];    // 10 KB: per-wave P (16q x 32k)
    __shared__ float Om[4][16 * OSTR];    // 16.6 KB: group-1 O partials
    __shared__ float2 mlbuf[4][16];

    const int b    = blockIdx.y;
    const int q0   = blockIdx.x * 64;
    const int t    = threadIdx.x;
    const int w    = t >> 6;        // wave 0..7
    const int s    = w & 3;         // query stripe (rows 16s..16s+15)
    const int g    = w >> 2;        // key group (tiles {2g, 2g+1})
    const int lane = t & 63;
    const int cl   = lane & 15;
    const int quad = lane >> 4;
    const int ql   = 4 * quad;

    const float4* qkv4 = (const float4*)qkv;   // 48 float4 per (b,seq) row
    const int c0 = (q0 >= 256) ? 0 : (4 - (q0 >> 6));

    // ---- issue ALL window loads up front (20 dwordx4 in flight) ----
    // staging role: thread = (key=lane, dim-slice 8w..8w+7)
    float4 kA[5], kB[5], vA[5], vB[5];
    #pragma unroll
    for (int c = 0; c < 5; ++c) {
        int kb = q0 - 256 + 64 * c; if (kb < 0) kb = 0;   // clamp (unused rows)
        const size_t base = (size_t)(b * 4096 + kb + lane) * 48 + 2 * w;
        kA[c] = qkv4[base + 16];
        kB[c] = qkv4[base + 17];
        vA[c] = qkv4[base + 32];
        vB[c] = qkv4[base + 33];
    }

    // ---- Q fragments: global -> reg directly (scale 1/8 exact) ----
    frag qf0, qf1;
    {
        const size_t qrow = (size_t)(b * 4096 + q0 + 16 * s + cl) * 48;
        float4 qa = qkv4[qrow + 2 * quad];
        float4 qb = qkv4[qrow + 2 * quad + 1];
        float4 qc = qkv4[qrow + 8 + 2 * quad];
        float4 qd = qkv4[qrow + 8 + 2 * quad + 1];
        qf0 = cvt8(qa, qb, 0.125f);
        qf1 = cvt8(qc, qd, 0.125f);
    }

    // ---- convert + stage the whole window ----
    #pragma unroll
    for (int c = 0; c < 5; ++c) {
        // K: one b128 write, even bank spread
        *(frag*)&Ks[(64 * c + lane) * KSTR + 8 * w] = cvt8(kA[c], kB[c], 1.0f);
        // V transpose: scalar b16 writes, bank = key/2 within wave (no conflict)
        const int col = 64 * c + lane;
        const int d0  = 8 * w;
        Vt[(d0 + 0) * VSTR + col] = f2bf(vA[c].x);
        Vt[(d0 + 1) * VSTR + col] = f2bf(vA[c].y);
        Vt[(d0 + 2) * VSTR + col] = f2bf(vA[c].z);
        Vt[(d0 + 3) * VSTR + col] = f2bf(vA[c].w);
        Vt[(d0 + 4) * VSTR + col] = f2bf(vB[c].x);
        Vt[(d0 + 5) * VSTR + col] = f2bf(vB[c].y);
        Vt[(d0 + 6) * VSTR + col] = f2bf(vB[c].z);
        Vt[(d0 + 7) * VSTR + col] = f2bf(vB[c].w);
    }
    __syncthreads();   // the ONLY staging barrier

    float m[4], l[4];
    f32x4 oacc[4];
    #pragma unroll
    for (int r = 0; r < 4; ++r) { m[r] = -1e30f; l[r] = 0.f; }
    #pragma unroll
    for (int n4 = 0; n4 < 4; ++n4) oacc[n4] = (f32x4){0.f, 0.f, 0.f, 0.f};

    // ---- barrier-free compute over chunks c0..4 ----
    for (int c = c0; c < 5; ++c) {
        // S = Q K^T over this group's 2 key-tiles
        f32x4 sc[2];
        #pragma unroll
        for (int u = 0; u < 2; ++u) {
            const int row = 64 * c + 16 * (2 * g + u) + cl;
            sc[u] = (f32x4){0.f, 0.f, 0.f, 0.f};
            const frag kf0 = *(const frag*)&Ks[row * KSTR + 8 * quad];
            const frag kf1 = *(const frag*)&Ks[row * KSTR + 32 + 8 * quad];
            sc[u] = __builtin_amdgcn_mfma_f32_16x16x32_bf16(qf0, kf0, sc[u], 0, 0, 0);
            sc[u] = __builtin_amdgcn_mfma_f32_16x16x32_bf16(qf1, kf1, sc[u], 0, 0, 0);
        }

        // sliding-window mask (edge chunks only; middle chunks always valid)
        if (c == 4) {           // causal: keep key <= query
            #pragma unroll
            for (int u = 0; u < 2; ++u) {
                const int t4 = 2 * g + u;
                #pragma unroll
                for (int r = 0; r < 4; ++r)
                    if (16 * s + ql + r < 16 * t4 + cl) sc[u][r] = -1e30f;
            }
        } else if (c == 0) {    // left edge: keep key >= query
            #pragma unroll
            for (int u = 0; u < 2; ++u) {
                const int t4 = 2 * g + u;
                #pragma unroll
                for (int r = 0; r < 4; ++r)
                    if (16 * s + ql + r > 16 * t4 + cl) sc[u][r] = -1e30f;
            }
        }

        // online softmax (DPP reductions; guard for fully-masked tiles)
        #pragma unroll
        for (int r = 0; r < 4; ++r) {
            float mx = red16_max(fmaxf(sc[0][r], sc[1][r]));
            const float mnew  = fmaxf(m[r], mx);
            const float alpha = __builtin_amdgcn_exp2f((m[r] - mnew) * LOG2E);
            m[r] = mnew;
            float sum = 0.f;
            #pragma unroll
            for (int u = 0; u < 2; ++u) {
                float p = (sc[u][r] <= -1e29f)
                            ? 0.f
                            : __builtin_amdgcn_exp2f((sc[u][r] - mnew) * LOG2E);
                Pw[w][(ql + r) * PSTR + 16 * u + cl] = f2bf(p);
                sum += p;
            }
            l[r] = l[r] * alpha + red16_sum(sum);
            #pragma unroll
            for (int n4 = 0; n4 < 4; ++n4) oacc[n4][r] *= alpha;
        }

        // O += P V (P wave-private: lgkmcnt only, no barrier)
        const frag pf = *(const frag*)&Pw[w][cl * PSTR + 8 * quad];
        #pragma unroll
        for (int n4 = 0; n4 < 4; ++n4) {
            const frag vf = *(const frag*)&Vt[(16 * n4 + cl) * VSTR
                                              + 64 * c + 32 * g + 8 * quad];
            oacc[n4] = __builtin_amdgcn_mfma_f32_16x16x32_bf16(pf, vf, oacc[n4], 0, 0, 0);
        }
    }

    // ---- merge the two key-groups per stripe ----
    if (g == 1) {
        #pragma unroll
        for (int n4 = 0; n4 < 4; ++n4)
            #pragma unroll
            for (int r = 0; r < 4; ++r)
                Om[s][(ql + r) * OSTR + 16 * n4 + cl] = oacc[n4][r];
        if (cl == 0)
            #pragma unroll
            for (int r = 0; r < 4; ++r)
                mlbuf[s][ql + r] = make_float2(m[r], l[r]);
    }
    __syncthreads();
    if (g == 0) {
        #pragma unroll
        for (int r = 0; r < 4; ++r) {
            const float2 ml1 = mlbuf[s][ql + r];
            const float M  = fmaxf(m[r], ml1.x);
            const float a0 = __builtin_amdgcn_exp2f((m[r]  - M) * LOG2E);
            const float a1 = __builtin_amdgcn_exp2f((ml1.x - M) * LOG2E);
            const float L  = l[r] * a0 + ml1.y * a1;
            const float inv = 1.0f / L;
            const size_t row = (size_t)(b * 4096 + q0 + 16 * s + ql + r) * 64;
            #pragma unroll
            for (int n4 = 0; n4 < 4; ++n4) {
                const float o1 = Om[s][(ql + r) * OSTR + 16 * n4 + cl];
                out[row + 16 * n4 + cl] = (oacc[n4][r] * a0 + o1 * a1) * inv;
            }
        }
    }
}

extern "C" void kernel_launch(void* const* d_in, const int* in_sizes, int n_in,
                              void* d_out, int out_size, void* d_ws, size_t ws_size,
                              hipStream_t stream) {
    const float* qkv = (const float*)d_in[0];
    float* out = (float*)d_out;
    dim3 grid(64, 4);
    dim3 block(512);
    hipLaunchKernelGGL(swa_mfma3, grid, block, 0, stream, qkv, out);
}